// Round 4
// baseline (263.263 us; speedup 1.0000x reference)
//
#include <hip/hip_runtime.h>
#include <hip/hip_bf16.h>

// Problem constants (fixed by setup_inputs): N=2048, d=256, T=256, Q=64
#define NN   2048
#define DD   256
#define TT   256
#define NYC  16384                 // T*Q flattened y columns
#define NCOLS (NYC + NN)           // 18432 total B columns (y then x)
#define NCHUNK_XY 64               // y chunks of 256 cols
#define NCHUNK_XX 8                // x chunks of 256 cols
#define NCHUNKS (NCHUNK_XY + NCHUNK_XX)
#define NFRAG (NCOLS / 16 * 8 * 64)   // 589824 fragment slots (8 bf16 each)

static constexpr float INV_TEMP = 1.0f / 0.3f;

typedef __bf16 bf16x8 __attribute__((ext_vector_type(8)));
typedef __bf16 bf16x4 __attribute__((ext_vector_type(4)));
typedef float  f32x4  __attribute__((ext_vector_type(4)));

__device__ __forceinline__ float bfr(float v) { return (float)(__bf16)v; }

// ------------------------------------------------------------------ prep
// One kernel: zero accumulators, diag[i]=exp(|bf16(x_i)|^2/T), x->bf16
// row-major (A operand), and B (y cols then x cols) -> bf16 in
// MFMA-fragment order. Element address for (tile g, kstep ks, lane, j):
//   g*4096 + ks*512 + lane*8 + j
// holding B[col = g*16 + (lane&15)][k = ks*32 + (lane>>4)*8 + j].
__global__ void prep_kernel(const float* __restrict__ x, const float* __restrict__ y,
                            __bf16* __restrict__ xbf, __bf16* __restrict__ cols,
                            float* __restrict__ acc, float* __restrict__ diag) {
    const int t0 = blockIdx.x * 256 + threadIdx.x;     // grid 1024 -> 262144 threads

    if (t0 < 3 * NN) acc[t0] = 0.f;

    if (t0 < NN * 8) {             // diag: 8 threads per row, 32 elems each
        const int row = t0 >> 3, sub = t0 & 7;
        const float4* xr = (const float4*)(x + (size_t)row * DD) + sub * 8;
        float s = 0.f;
#pragma unroll
        for (int u = 0; u < 8; u++) {
            float4 v = xr[u];
            float a = bfr(v.x), b = bfr(v.y), c = bfr(v.z), d = bfr(v.w);
            s += a * a + b * b + c * c + d * d;
        }
        s += __shfl_xor(s, 1); s += __shfl_xor(s, 2); s += __shfl_xor(s, 4);
        if (sub == 0) diag[row] = __expf(s * INV_TEMP);
    }

    if (t0 < NN * DD / 4) {        // x -> bf16 row-major
        float4 v = ((const float4*)x)[t0];
        bf16x4 o; o[0] = (__bf16)v.x; o[1] = (__bf16)v.y; o[2] = (__bf16)v.z; o[3] = (__bf16)v.w;
        *(bf16x4*)(xbf + 4 * (size_t)t0) = o;
    }

    for (int f = t0; f < NFRAG; f += 262144) {   // B fragment swizzle
        const int lane = f & 63, ks = (f >> 6) & 7, g = f >> 9;
        const int col  = g * 16 + (lane & 15);
        const int koff = ks * 32 + (lane >> 4) * 8;
        const float* src = (col < NYC ? y + (size_t)col * DD
                                      : x + (size_t)(col - NYC) * DD) + koff;
        float4 v0 = *(const float4*)src, v1 = *(const float4*)(src + 4);
        bf16x8 o;
        o[0] = (__bf16)v0.x; o[1] = (__bf16)v0.y; o[2] = (__bf16)v0.z; o[3] = (__bf16)v0.w;
        o[4] = (__bf16)v1.x; o[5] = (__bf16)v1.y; o[6] = (__bf16)v1.z; o[7] = (__bf16)v1.w;
        *(bf16x8*)(cols + (size_t)f * 8) = o;
    }
}

// ------------------------------------------------------------------ stats
// Grid (16, 72): x = 128-row block (4 waves x 32 rows), y = chunk.
// No LDS, no barriers: B fragments stream from global (fragment-order,
// perfectly coalesced dwordx4), register double-buffered 2 tiles deep.
__global__ void stats_kernel(const __bf16* __restrict__ xbf, const __bf16* __restrict__ cols,
                             const int* __restrict__ tid,
                             float* __restrict__ Tot, float* __restrict__ Pxy,
                             float* __restrict__ Pxx) {
    const int w    = threadIdx.x >> 6;
    const int lane = threadIdx.x & 63;
    const int c16  = lane & 15;
    const int q    = lane >> 4;
    const int rowbase = blockIdx.x * 128 + w * 32;
    const int chunk   = blockIdx.y;
    const int mode    = (chunk >= NCHUNK_XY);   // 0: y cols, 1: x cols

    // A fragments: this wave's 32 rows, full K=256.
    bf16x8 afrag[2][8];
#pragma unroll
    for (int t = 0; t < 2; t++) {
        const __bf16* base = xbf + (size_t)(rowbase + t * 16 + c16) * DD + q * 8;
#pragma unroll
        for (int ks = 0; ks < 8; ks++)
            afrag[t][ks] = *(const bf16x8*)(base + ks * 32);
    }
    int tidrow[2][4];
#pragma unroll
    for (int t = 0; t < 2; t++)
#pragma unroll
        for (int r = 0; r < 4; r++)
            tidrow[t][r] = tid[rowbase + t * 16 + q * 4 + r];

    float tot[2][4] = {}, pos[2][4] = {};

    // fragment base for this lane within this chunk (tile stride 4096 elems,
    // ks stride 512 elems, lane stride 8 elems)
    const __bf16* fb = cols + ((size_t)chunk * 16 * 512 + lane) * 8;

    bf16x8 b0[8], b1[8];
#pragma unroll
    for (int ks = 0; ks < 8; ks++) b0[ks] = *(const bf16x8*)(fb + ks * 512);

    auto epilogue = [&](const f32x4& a0, const f32x4& a1, int ct) {
        int coltid;
        if (!mode) coltid = ct * 16 + c16;                       // y track id = col % 256
        else       coltid = tid[(chunk - NCHUNK_XY) * 256 + ct * 16 + c16];
#pragma unroll
        for (int t = 0; t < 2; t++) {
            const f32x4& a = t ? a1 : a0;
#pragma unroll
            for (int r = 0; r < 4; r++) {
                float val = __expf(a[r] * INV_TEMP);
                tot[t][r] += val;
                pos[t][r] += (coltid == tidrow[t][r]) ? val : 0.f;
            }
        }
    };

    for (int ct = 0; ct < 16; ct += 2) {
        // prefetch tile ct+1 (ct+1 <= 15 always)
        {
            const __bf16* nb = fb + (size_t)(ct + 1) * 4096;
#pragma unroll
            for (int ks = 0; ks < 8; ks++) b1[ks] = *(const bf16x8*)(nb + ks * 512);
        }
        f32x4 acc0 = {0.f, 0.f, 0.f, 0.f}, acc1 = {0.f, 0.f, 0.f, 0.f};
#pragma unroll
        for (int ks = 0; ks < 8; ks++) {
            acc0 = __builtin_amdgcn_mfma_f32_16x16x32_bf16(afrag[0][ks], b0[ks], acc0, 0, 0, 0);
            acc1 = __builtin_amdgcn_mfma_f32_16x16x32_bf16(afrag[1][ks], b0[ks], acc1, 0, 0, 0);
        }
        epilogue(acc0, acc1, ct);

        if (ct + 2 < 16) {
            const __bf16* nb = fb + (size_t)(ct + 2) * 4096;
#pragma unroll
            for (int ks = 0; ks < 8; ks++) b0[ks] = *(const bf16x8*)(nb + ks * 512);
        }
        acc0 = (f32x4){0.f, 0.f, 0.f, 0.f}; acc1 = (f32x4){0.f, 0.f, 0.f, 0.f};
#pragma unroll
        for (int ks = 0; ks < 8; ks++) {
            acc0 = __builtin_amdgcn_mfma_f32_16x16x32_bf16(afrag[0][ks], b1[ks], acc0, 0, 0, 0);
            acc1 = __builtin_amdgcn_mfma_f32_16x16x32_bf16(afrag[1][ks], b1[ks], acc1, 0, 0, 0);
        }
        epilogue(acc0, acc1, ct + 1);
    }

    // Reduce over the 16 column-lanes sharing (q,r); one atomic per row.
#pragma unroll
    for (int t = 0; t < 2; t++)
#pragma unroll
        for (int r = 0; r < 4; r++) {
            float a = tot[t][r], p = pos[t][r];
#pragma unroll
            for (int off = 1; off < 16; off <<= 1) {
                a += __shfl_xor(a, off);
                p += __shfl_xor(p, off);
            }
            if (c16 == 0) {
                const int row = rowbase + t * 16 + q * 4 + r;
                atomicAdd(&Tot[row], a);
                atomicAdd(mode ? &Pxx[row] : &Pxy[row], p);
            }
        }
}

// ------------------------------------------------------------------ finalize
__global__ void finalize_kernel(const float* __restrict__ Tot, const float* __restrict__ Pxy,
                                const float* __restrict__ Pxx, const float* __restrict__ diag,
                                const int* __restrict__ tid, float* __restrict__ out) {
    __shared__ float num_s[TT], den_s[TT];
    __shared__ int cnt_s[TT];
    const int t = threadIdx.x;  // 256 threads
    num_s[t] = 0.f; den_s[t] = 0.f; cnt_s[t] = 0;
    __syncthreads();
    for (int i = t; i < NN; i += 256) {
        float tt_ = Tot[i], pxy = Pxy[i], pxx = Pxx[i];
        float num = pxy + 0.5f * (pxx - diag[i]);
        float den = tt_ - pxy - pxx;
        int tr = tid[i];
        atomicAdd(&num_s[tr], num);
        atomicAdd(&den_s[tr], den);
        atomicAdd(&cnt_s[tr], 1);
    }
    __syncthreads();
    float lt = 0.f, pr = 0.f;
    if (cnt_s[t] > 0) {
        lt = -logf(num_s[t] / (den_s[t] + num_s[t]));
        pr = 1.f;
    }
    for (int off = 32; off; off >>= 1) { lt += __shfl_down(lt, off); pr += __shfl_down(pr, off); }
    __shared__ float ls[4], ps[4];
    if ((t & 63) == 0) { ls[t >> 6] = lt; ps[t >> 6] = pr; }
    __syncthreads();
    if (t == 0) out[0] = (ls[0] + ls[1] + ls[2] + ls[3]) / (ps[0] + ps[1] + ps[2] + ps[3]);
}

// ------------------------------------------------------------------ launch
extern "C" void kernel_launch(void* const* d_in, const int* in_sizes, int n_in,
                              void* d_out, int out_size, void* d_ws, size_t ws_size,
                              hipStream_t stream) {
    const float* x   = (const float*)d_in[0];
    const int*   tid = (const int*)d_in[1];
    const float* y   = (const float*)d_in[2];
    float* out = (float*)d_out;

    char* ws = (char*)d_ws;
    __bf16* xbf  = (__bf16*)ws;                        // 1 MB (A, row-major)
    __bf16* cols = (__bf16*)(ws + (1u << 20));         // 9.4 MB (B, fragment order)
    float* acc   = (float*)(ws + 11u * (1u << 20));    // Tot,Pxy,Pxx
    float* Tot   = acc;
    float* Pxy   = acc + NN;
    float* Pxx   = acc + 2 * NN;
    float* diag  = acc + 3 * NN;

    prep_kernel<<<1024, 256, 0, stream>>>(x, y, xbf, cols, acc, diag);
    stats_kernel<<<dim3(16, NCHUNKS), 256, 0, stream>>>(xbf, cols, tid, Tot, Pxy, Pxx);
    finalize_kernel<<<1, 256, 0, stream>>>(Tot, Pxy, Pxx, diag, tid, out);
}

// Round 5
// 149.923 us; speedup vs baseline: 1.7560x; 1.7560x over previous
//
#include <hip/hip_runtime.h>
#include <hip/hip_bf16.h>

// Problem constants (fixed by setup_inputs): N=2048, d=256, T=256, Q=64
#define NN   2048
#define DD   256
#define TT   256
#define NYC  16384                 // T*Q flattened y columns
#define NCOLS (NYC + NN)           // 18432 total B columns (y then x)
#define NCHUNK_XY 64               // y chunks of 256 cols
#define NCHUNK_XX 8                // x chunks of 256 cols
#define NCHUNKS (NCHUNK_XY + NCHUNK_XX)
#define NROWBLK 16                 // 2048 / 128 rows per block
#define NFRAG (NCOLS / 16 * 8 * 64)   // 589824 fragment slots (8 bf16 each)

static constexpr float INV_TEMP = 1.0f / 0.3f;

typedef __bf16 bf16x8 __attribute__((ext_vector_type(8)));
typedef __bf16 bf16x4 __attribute__((ext_vector_type(4)));
typedef float  f32x4  __attribute__((ext_vector_type(4)));

__device__ __forceinline__ float bfr(float v) { return (float)(__bf16)v; }

// ------------------------------------------------------------------ prep
// Zero accumulators, diag[i]=exp(|bf16(x_i)|^2/T), x->bf16 row-major (A),
// and B (y cols then x cols) -> bf16 in MFMA-fragment order. Element address
// for (tile g, kstep ks, lane, j): g*4096 + ks*512 + lane*8 + j, holding
// B[col = g*16 + (lane&15)][k = ks*32 + (lane>>4)*8 + j].
__global__ void prep_kernel(const float* __restrict__ x, const float* __restrict__ y,
                            __bf16* __restrict__ xbf, __bf16* __restrict__ cols,
                            float* __restrict__ acc, float* __restrict__ diag) {
    const int t0 = blockIdx.x * 256 + threadIdx.x;     // grid 1024 -> 262144 threads

    if (t0 < 3 * NN) acc[t0] = 0.f;

    if (t0 < NN * 8) {             // diag: 8 threads per row, 32 elems each
        const int row = t0 >> 3, sub = t0 & 7;
        const float4* xr = (const float4*)(x + (size_t)row * DD) + sub * 8;
        float s = 0.f;
#pragma unroll
        for (int u = 0; u < 8; u++) {
            float4 v = xr[u];
            float a = bfr(v.x), b = bfr(v.y), c = bfr(v.z), d = bfr(v.w);
            s += a * a + b * b + c * c + d * d;
        }
        s += __shfl_xor(s, 1); s += __shfl_xor(s, 2); s += __shfl_xor(s, 4);
        if (sub == 0) diag[row] = __expf(s * INV_TEMP);
    }

    if (t0 < NN * DD / 4) {        // x -> bf16 row-major
        float4 v = ((const float4*)x)[t0];
        bf16x4 o; o[0] = (__bf16)v.x; o[1] = (__bf16)v.y; o[2] = (__bf16)v.z; o[3] = (__bf16)v.w;
        *(bf16x4*)(xbf + 4 * (size_t)t0) = o;
    }

    for (int f = t0; f < NFRAG; f += 262144) {   // B fragment swizzle
        const int lane = f & 63, ks = (f >> 6) & 7, g = f >> 9;
        const int col  = g * 16 + (lane & 15);
        const int koff = ks * 32 + (lane >> 4) * 8;
        const float* src = (col < NYC ? y + (size_t)col * DD
                                      : x + (size_t)(col - NYC) * DD) + koff;
        float4 v0 = *(const float4*)src, v1 = *(const float4*)(src + 4);
        bf16x8 o;
        o[0] = (__bf16)v0.x; o[1] = (__bf16)v0.y; o[2] = (__bf16)v0.z; o[3] = (__bf16)v0.w;
        o[4] = (__bf16)v1.x; o[5] = (__bf16)v1.y; o[6] = (__bf16)v1.z; o[7] = (__bf16)v1.w;
        *(bf16x8*)(cols + (size_t)f * 8) = o;
    }
}

// ------------------------------------------------------------------ stats
// 1152 blocks, swizzled so a chunk's 16 row-blocks share an XCD (L2 reuse).
// Block = 4 waves x 32 rows = 128 rows, 256 chunk cols. Per 16-col tile the
// block stages the 8 KB fragment-order tile into LDS (coalesced float4 pairs,
// double-buffered, ONE barrier/tile with loads issued right after it).
__global__ void __launch_bounds__(256)
stats_kernel(const __bf16* __restrict__ xbf, const __bf16* __restrict__ cols,
             const int* __restrict__ tid,
             float* __restrict__ Tot, float* __restrict__ Pxy,
             float* __restrict__ Pxx) {
    __shared__ __align__(16) char bstage[2][8192];

    const int tix  = threadIdx.x;
    const int w    = tix >> 6;
    const int lane = tix & 63;
    const int c16  = lane & 15;
    const int q    = lane >> 4;

    // XCD-aware swizzle: chunk c runs only on XCD c%8.
    const int L     = blockIdx.x;
    const int xcd   = L & 7;
    const int slot  = L >> 3;              // 0..143
    const int chunk = (slot % 9) * 8 + xcd;   // 0..71
    const int rowblk = slot / 9;              // 0..15
    const int mode  = (chunk >= NCHUNK_XY);   // 0: y cols, 1: x cols
    const int rowbase = rowblk * 128 + w * 32;

    // A fragments: this wave's 32 rows, full K=256 (64 VGPRs).
    bf16x8 afrag[2][8];
#pragma unroll
    for (int t = 0; t < 2; t++) {
        const __bf16* base = xbf + (size_t)(rowbase + t * 16 + c16) * DD + q * 8;
#pragma unroll
        for (int ks = 0; ks < 8; ks++)
            afrag[t][ks] = *(const bf16x8*)(base + ks * 32);
    }
    int tidrow[2][4];
#pragma unroll
    for (int t = 0; t < 2; t++)
#pragma unroll
        for (int r = 0; r < 4; r++)
            tidrow[t][r] = tid[rowbase + t * 16 + q * 4 + r];

    float tot[2][4] = {}, pos[2][4] = {};

    // tile base in fragment-order cols: tile g = chunk*16 + ct, 4096 elems each
    const float4* tile0 = (const float4*)(cols + (size_t)chunk * 16 * 4096);

    float4 pf0 = tile0[tix * 2];
    float4 pf1 = tile0[tix * 2 + 1];

    for (int ct = 0; ct < 16; ct++) {
        // write prefetched tile into LDS buffer ct&1
        float4* d4 = (float4*)&bstage[ct & 1][tix * 32];
        d4[0] = pf0; d4[1] = pf1;
        __syncthreads();   // nothing outstanding in vmcnt here (pf consumed)

        if (ct < 15) {     // issue next tile's loads; they land during compute
            const float4* nt = tile0 + (ct + 1) * 512;
            pf0 = nt[tix * 2];
            pf1 = nt[tix * 2 + 1];
        }

        const char* bb = &bstage[ct & 1][lane * 16];
        f32x4 acc0 = {0.f, 0.f, 0.f, 0.f}, acc1 = {0.f, 0.f, 0.f, 0.f};
#pragma unroll
        for (int ks = 0; ks < 8; ks++) {
            bf16x8 b = *(const bf16x8*)(bb + ks * 1024);
            acc0 = __builtin_amdgcn_mfma_f32_16x16x32_bf16(afrag[0][ks], b, acc0, 0, 0, 0);
            acc1 = __builtin_amdgcn_mfma_f32_16x16x32_bf16(afrag[1][ks], b, acc1, 0, 0, 0);
        }

        int coltid;
        if (!mode) coltid = ct * 16 + c16;    // y track id = col % 256
        else       coltid = tid[(chunk - NCHUNK_XY) * 256 + ct * 16 + c16];
#pragma unroll
        for (int t = 0; t < 2; t++) {
            const f32x4& a = t ? acc1 : acc0;
#pragma unroll
            for (int r = 0; r < 4; r++) {
                float val = __expf(a[r] * INV_TEMP);
                tot[t][r] += val;
                pos[t][r] += (coltid == tidrow[t][r]) ? val : 0.f;
            }
        }
        __syncthreads();   // all waves done reading buf[ct&1] before its rewrite
    }

    // Reduce over the 16 column-lanes sharing (q,r); one atomic per row.
#pragma unroll
    for (int t = 0; t < 2; t++)
#pragma unroll
        for (int r = 0; r < 4; r++) {
            float a = tot[t][r], p = pos[t][r];
#pragma unroll
            for (int off = 1; off < 16; off <<= 1) {
                a += __shfl_xor(a, off);
                p += __shfl_xor(p, off);
            }
            if (c16 == 0) {
                const int row = rowbase + t * 16 + q * 4 + r;
                atomicAdd(&Tot[row], a);
                atomicAdd(mode ? &Pxx[row] : &Pxy[row], p);
            }
        }
}

// ------------------------------------------------------------------ finalize
__global__ void finalize_kernel(const float* __restrict__ Tot, const float* __restrict__ Pxy,
                                const float* __restrict__ Pxx, const float* __restrict__ diag,
                                const int* __restrict__ tid, float* __restrict__ out) {
    __shared__ float num_s[TT], den_s[TT];
    __shared__ int cnt_s[TT];
    const int t = threadIdx.x;  // 256 threads
    num_s[t] = 0.f; den_s[t] = 0.f; cnt_s[t] = 0;
    __syncthreads();
    for (int i = t; i < NN; i += 256) {
        float tt_ = Tot[i], pxy = Pxy[i], pxx = Pxx[i];
        float num = pxy + 0.5f * (pxx - diag[i]);
        float den = tt_ - pxy - pxx;
        int tr = tid[i];
        atomicAdd(&num_s[tr], num);
        atomicAdd(&den_s[tr], den);
        atomicAdd(&cnt_s[tr], 1);
    }
    __syncthreads();
    float lt = 0.f, pr = 0.f;
    if (cnt_s[t] > 0) {
        lt = -logf(num_s[t] / (den_s[t] + num_s[t]));
        pr = 1.f;
    }
    for (int off = 32; off; off >>= 1) { lt += __shfl_down(lt, off); pr += __shfl_down(pr, off); }
    __shared__ float ls[4], ps[4];
    if ((t & 63) == 0) { ls[t >> 6] = lt; ps[t >> 6] = pr; }
    __syncthreads();
    if (t == 0) out[0] = (ls[0] + ls[1] + ls[2] + ls[3]) / (ps[0] + ps[1] + ps[2] + ps[3]);
}

// ------------------------------------------------------------------ launch
extern "C" void kernel_launch(void* const* d_in, const int* in_sizes, int n_in,
                              void* d_out, int out_size, void* d_ws, size_t ws_size,
                              hipStream_t stream) {
    const float* x   = (const float*)d_in[0];
    const int*   tid = (const int*)d_in[1];
    const float* y   = (const float*)d_in[2];
    float* out = (float*)d_out;

    char* ws = (char*)d_ws;
    __bf16* xbf  = (__bf16*)ws;                        // 1 MB (A, row-major)
    __bf16* cols = (__bf16*)(ws + (1u << 20));         // 9.4 MB (B, fragment order)
    float* acc   = (float*)(ws + 11u * (1u << 20));    // Tot,Pxy,Pxx
    float* Tot   = acc;
    float* Pxy   = acc + NN;
    float* Pxx   = acc + 2 * NN;
    float* diag  = acc + 3 * NN;

    prep_kernel<<<1024, 256, 0, stream>>>(x, y, xbf, cols, acc, diag);
    stats_kernel<<<NROWBLK * NCHUNKS, 256, 0, stream>>>(xbf, cols, tid, Tot, Pxy, Pxx);
    finalize_kernel<<<1, 256, 0, stream>>>(Tot, Pxy, Pxx, diag, tid, out);
}